// Round 2
// baseline (1489.618 us; speedup 1.0000x reference)
//
#include <hip/hip_runtime.h>

// CapsuleMappingTiny: fused  l2norm(k) @ l2norm(q)^T -> LN1 -> @v -> LN2
// B=32, N=1024, D=256 fp32.
// LN1 commutes through GEMM2:
//   out[k,d] = inv_k*(S[k,d] - mu_k*c1[d]) + c2[d]
//   S = m @ (g1*v),  c1 = sum_q g1[q] v[q,:],  c2 = sum_q b1[q] v[q,:]
// so the 32x1024x1024 mapping tensor is never materialized.

#define KT 64
#define QT 64
#define NT 16   // 1024 / QT

// float4-quad XOR swizzle inside a [row][256 floats] tile.
// Per-lane rows advance by 4 in the GEMM loops, so key the swizzle on row>>2.
__device__ __forceinline__ int swz(int r, int d4) {
    return r * 256 + (((d4) ^ ((r >> 2) & 7)) << 2);
}

__device__ __forceinline__ void stage_tile(const float* __restrict__ src,
                                           float* dst, int w, int l) {
    // 64 rows x 256 floats; wave w stages rows i*4+w; lane l does float4 at d=l*4.
    #pragma unroll
    for (int i = 0; i < 16; ++i) {
        const int r = i * 4 + w;
        const float4 t = *(const float4*)(src + r * 256 + l * 4);
        *(float4*)(dst + swz(r, l)) = t;
    }
}

__device__ __forceinline__ void normalize_rows(float* tile, int tid) {
    // 4 threads per row, 64 floats each. l2-normalize with eps=1e-12.
    const int r = tid >> 2, qu = tid & 3;
    float ss = 0.f;
    #pragma unroll
    for (int j = 0; j < 16; ++j) {
        const float4 a = *(const float4*)(tile + swz(r, qu * 16 + j));
        ss += a.x * a.x + a.y * a.y + a.z * a.z + a.w * a.w;
    }
    ss += __shfl_xor(ss, 1);
    ss += __shfl_xor(ss, 2);
    const float sc = rsqrtf(fmaxf(ss, 1e-12f));
    #pragma unroll
    for (int j = 0; j < 16; ++j) {
        float4 a = *(const float4*)(tile + swz(r, qu * 16 + j));
        a.x *= sc; a.y *= sc; a.z *= sc; a.w *= sc;
        *(float4*)(tile + swz(r, qu * 16 + j)) = a;
    }
}

__global__ __launch_bounds__(256, 1)
void capsule_fused_kernel(const float* __restrict__ kin,
                          const float* __restrict__ qin,
                          const float* __restrict__ vin,
                          const float* __restrict__ g1,
                          const float* __restrict__ b1,
                          const float* __restrict__ g2,
                          const float* __restrict__ b2,
                          float* __restrict__ out)
{
    __shared__ __align__(16) float knl[64 * 256];   // 64 KB, normalized K tile
    __shared__ __align__(16) float qvl[64 * 256];   // 64 KB, q-norm tile then v tile
    __shared__ __align__(16) float mT[64 * 68];     // m^T[qq][r], stride 68 (17 KB)
    __shared__ float g1s[64], b1s[64];
    __shared__ float muv[64], invv[64];

    const int tid = threadIdx.x;
    const int w = tid >> 6, l = tid & 63;
    const int ty = tid >> 4, tx = tid & 15;
    const int b  = blockIdx.x >> 4;
    const int kt = blockIdx.x & 15;

    const float* kb = kin + (size_t)(b * 1024 + kt * 64) * 256;
    const float* qb = qin + (size_t)b * 1024 * 256;
    const float* vb = vin + (size_t)b * 1024 * 256;

    // ---- stage + normalize K tile (once) ----
    stage_tile(kb, knl, w, l);
    __syncthreads();
    normalize_rows(knl, tid);
    // visibility handled by loop-top barrier

    // persistent accumulators
    float out_acc[4][4][4];   // [i: row 4ty+i][j: col chunk j*64+tx*4][e]
    float c1p[4][4], c2p[4][4];
    float rs[4] = {0.f, 0.f, 0.f, 0.f}, rss[4] = {0.f, 0.f, 0.f, 0.f};
    #pragma unroll
    for (int i = 0; i < 4; ++i)
        #pragma unroll
        for (int j = 0; j < 4; ++j) {
            c1p[i][j] = 0.f; c2p[i][j] = 0.f;
            #pragma unroll
            for (int e = 0; e < 4; ++e) out_acc[i][j][e] = 0.f;
        }

    const int sK = tx & 7;
    const int sQ = ty & 7;

    for (int qt = 0; qt < NT; ++qt) {
        const int qoff = qt * QT;
        __syncthreads();                       // qvl free; (iter0) kn normalize visible
        stage_tile(qb + (size_t)qoff * 256, qvl, w, l);
        if (tid < 64) { g1s[tid] = g1[qoff + tid]; b1s[tid] = b1[qoff + tid]; }
        __syncthreads();
        normalize_rows(qvl, tid);
        __syncthreads();

        // ---- GEMM1: m^T[qq=4ty+i][r=4tx+j] = qn[qq,:] . kn[r,:] ----
        float m_acc[4][4];
        #pragma unroll
        for (int i = 0; i < 4; ++i)
            #pragma unroll
            for (int j = 0; j < 4; ++j) m_acc[i][j] = 0.f;

        #pragma unroll 4
        for (int d4 = 0; d4 < 64; ++d4) {
            float4 qa[4], ka[4];
            const int oQ = ((d4 ^ sQ) << 2);
            const int oK = ((d4 ^ sK) << 2);
            #pragma unroll
            for (int i = 0; i < 4; ++i)
                qa[i] = *(const float4*)(qvl + (4 * ty + i) * 256 + oQ);
            #pragma unroll
            for (int j = 0; j < 4; ++j)
                ka[j] = *(const float4*)(knl + (4 * tx + j) * 256 + oK);
            #pragma unroll
            for (int i = 0; i < 4; ++i)
                #pragma unroll
                for (int j = 0; j < 4; ++j)
                    m_acc[i][j] += qa[i].x * ka[j].x + qa[i].y * ka[j].y +
                                   qa[i].z * ka[j].z + qa[i].w * ka[j].w;
        }

        // write m^T to LDS; accumulate raw row sums (for LN1 mu/var)
        #pragma unroll
        for (int i = 0; i < 4; ++i) {
            const float4 t = make_float4(m_acc[i][0], m_acc[i][1], m_acc[i][2], m_acc[i][3]);
            *(float4*)(mT + (4 * ty + i) * 68 + 4 * tx) = t;
        }
        #pragma unroll
        for (int j = 0; j < 4; ++j)
            #pragma unroll
            for (int i = 0; i < 4; ++i) {
                rs[j]  += m_acc[i][j];
                rss[j] += m_acc[i][j] * m_acc[i][j];
            }
        __syncthreads();                       // mT visible; qvl reads done
        stage_tile(vb + (size_t)qoff * 256, qvl, w, l);   // raw v tile
        __syncthreads();

        // ---- GEMM2: out_acc[r=4ty+i][c] += g1[qq]*m[r][qq]*v[qq][c] ----
        #pragma unroll 2
        for (int qq = 0; qq < 64; ++qq) {
            const int sV = (qq >> 2) & 7;
            const float4 m4 = *(const float4*)(mT + qq * 68 + 4 * ty);
            const float a = g1s[qq];
            const float t0 = a * m4.x, t1 = a * m4.y, t2 = a * m4.z, t3 = a * m4.w;
            #pragma unroll
            for (int j = 0; j < 4; ++j) {
                const float4 vv = *(const float4*)(qvl + qq * 256 + (((j * 16 + tx) ^ sV) << 2));
                out_acc[0][j][0] += t0 * vv.x; out_acc[0][j][1] += t0 * vv.y;
                out_acc[0][j][2] += t0 * vv.z; out_acc[0][j][3] += t0 * vv.w;
                out_acc[1][j][0] += t1 * vv.x; out_acc[1][j][1] += t1 * vv.y;
                out_acc[1][j][2] += t1 * vv.z; out_acc[1][j][3] += t1 * vv.w;
                out_acc[2][j][0] += t2 * vv.x; out_acc[2][j][1] += t2 * vv.y;
                out_acc[2][j][2] += t2 * vv.z; out_acc[2][j][3] += t2 * vv.w;
                out_acc[3][j][0] += t3 * vv.x; out_acc[3][j][1] += t3 * vv.y;
                out_acc[3][j][2] += t3 * vv.z; out_acc[3][j][3] += t3 * vv.w;
            }
        }
        // c1/c2 partials: this thread covers qq = 4ty..4ty+3
        #pragma unroll
        for (int i = 0; i < 4; ++i) {
            const int qq = 4 * ty + i;
            const float a1 = g1s[qq], a2 = b1s[qq];
            #pragma unroll
            for (int j = 0; j < 4; ++j) {
                const float4 vv = *(const float4*)(qvl + qq * 256 + (((j * 16 + tx) ^ sQ) << 2));
                c1p[j][0] += a1 * vv.x; c1p[j][1] += a1 * vv.y;
                c1p[j][2] += a1 * vv.z; c1p[j][3] += a1 * vv.w;
                c2p[j][0] += a2 * vv.x; c2p[j][1] += a2 * vv.y;
                c2p[j][2] += a2 * vv.z; c2p[j][3] += a2 * vv.w;
            }
        }
    }

    // ================= epilogue =================
    __syncthreads();
    float* red1  = mT;            // reuse (64*16 floats)
    float* red2  = mT + 1024;
    float* credA = knl;           // reuse: [16 ty][256 c]
    float* credB = qvl;

    #pragma unroll
    for (int j = 0; j < 4; ++j) {
        red1[(4 * tx + j) * 16 + ty] = rs[j];
        red2[(4 * tx + j) * 16 + ty] = rss[j];
    }
    #pragma unroll
    for (int j = 0; j < 4; ++j)
        #pragma unroll
        for (int e = 0; e < 4; ++e) {
            credA[ty * 256 + j * 64 + tx * 4 + e] = c1p[j][e];
            credB[ty * 256 + j * 64 + tx * 4 + e] = c2p[j][e];
        }
    __syncthreads();

    if (tid < 64) {
        float s = 0.f, ss = 0.f;
        #pragma unroll 4
        for (int t = 0; t < 16; ++t) { s += red1[tid * 16 + t]; ss += red2[tid * 16 + t]; }
        const float mu  = s * (1.f / 1024.f);
        const float var = ss * (1.f / 1024.f) - mu * mu;
        muv[tid]  = mu;
        invv[tid] = rsqrtf(var + 1e-3f);
    }
    float c1v[4][4], c2v[4][4];
    #pragma unroll
    for (int j = 0; j < 4; ++j)
        #pragma unroll
        for (int e = 0; e < 4; ++e) { c1v[j][e] = 0.f; c2v[j][e] = 0.f; }
    for (int t = 0; t < 16; ++t)
        #pragma unroll
        for (int j = 0; j < 4; ++j)
            #pragma unroll
            for (int e = 0; e < 4; ++e) {
                c1v[j][e] += credA[t * 256 + j * 64 + tx * 4 + e];
                c2v[j][e] += credB[t * 256 + j * 64 + tx * 4 + e];
            }
    __syncthreads();   // muv/invv ready; red1/red2 free for LN2

    // apply LN1-through-GEMM fixup, gather LN2 partials
    float s2[4] = {0.f, 0.f, 0.f, 0.f}, ss2[4] = {0.f, 0.f, 0.f, 0.f};
    #pragma unroll
    for (int i = 0; i < 4; ++i) {
        const int r = 4 * ty + i;
        const float mu = muv[r], inv = invv[r];
        #pragma unroll
        for (int j = 0; j < 4; ++j)
            #pragma unroll
            for (int e = 0; e < 4; ++e) {
                const float val = inv * (out_acc[i][j][e] - mu * c1v[j][e]) + c2v[j][e];
                out_acc[i][j][e] = val;
                s2[i]  += val;
                ss2[i] += val * val;
            }
    }
    #pragma unroll
    for (int i = 0; i < 4; ++i) {
        red1[(4 * ty + i) * 16 + tx] = s2[i];
        red2[(4 * ty + i) * 16 + tx] = ss2[i];
    }
    __syncthreads();
    if (tid < 64) {
        float s = 0.f, ss = 0.f;
        #pragma unroll 4
        for (int t = 0; t < 16; ++t) { s += red1[tid * 16 + t]; ss += red2[tid * 16 + t]; }
        const float mu  = s * (1.f / 256.f);
        const float var = ss * (1.f / 256.f) - mu * mu;
        muv[tid]  = mu;                 // reuse for LN2
        invv[tid] = rsqrtf(var + 1e-3f);
    }
    __syncthreads();

    #pragma unroll
    for (int i = 0; i < 4; ++i) {
        const int r = 4 * ty + i;
        const float mu = muv[r], inv = invv[r];
        #pragma unroll
        for (int j = 0; j < 4; ++j) {
            const int c0 = j * 64 + tx * 4;
            const float4 gg = *(const float4*)(g2 + c0);
            const float4 bb = *(const float4*)(b2 + c0);
            float4 o;
            o.x = (out_acc[i][j][0] - mu) * inv * gg.x + bb.x;
            o.y = (out_acc[i][j][1] - mu) * inv * gg.y + bb.y;
            o.z = (out_acc[i][j][2] - mu) * inv * gg.z + bb.z;
            o.w = (out_acc[i][j][3] - mu) * inv * gg.w + bb.w;
            *(float4*)(out + (size_t)(b * 1024 + kt * 64 + r) * 256 + c0) = o;
        }
    }
}

extern "C" void kernel_launch(void* const* d_in, const int* in_sizes, int n_in,
                              void* d_out, int out_size, void* d_ws, size_t ws_size,
                              hipStream_t stream) {
    const float* kin = (const float*)d_in[0];
    const float* qin = (const float*)d_in[1];
    const float* vin = (const float*)d_in[2];
    const float* g1  = (const float*)d_in[3];
    const float* b1  = (const float*)d_in[4];
    const float* g2  = (const float*)d_in[5];
    const float* b2  = (const float*)d_in[6];
    float* out = (float*)d_out;

    hipLaunchKernelGGL(capsule_fused_kernel, dim3(512), dim3(256), 0, stream,
                       kin, qin, vin, g1, b1, g2, b2, out);
}

// Round 5
// 665.009 us; speedup vs baseline: 2.2400x; 2.2400x over previous
//
#include <hip/hip_runtime.h>

// CapsuleMappingTiny on MFMA: l2n(k)@l2n(q)^T -> LN1 -> @v -> LN2, B=32,N=1024,D=256 fp32.
// fp32 emulated via split-bf16 3-pass MFMA (Ah*Bh + Ah*Bl + Al*Bh), 16x16x32.
// LN1 commutes through GEMM2: out[k,d] = inv_k*(S[k,d] - mu_k*c1[d]) + c2[d],
//   S = m_raw @ (g1*v), c1 = sum_q g1 v, c2 = sum_q b1 v.
// Block = (batch, 64-row k-tile); 512 blocks, 256 thr (4 waves).
// GEMM1: m[64k x 64q], wave w owns k-rows 16w..16w+15 (4 q-frags).
// GEMM2: out^T[256d x 64k], wave w owns d-rows 64w..64w+63 (4x4 frags, persistent).

typedef __attribute__((ext_vector_type(8))) short bf16x8;
typedef __attribute__((ext_vector_type(4))) float f32x4;
typedef __attribute__((ext_vector_type(4))) unsigned short u16x4;
typedef unsigned short u16;

#define MFMA(a, b, c) __builtin_amdgcn_mfma_f32_16x16x32_bf16((a), (b), (c), 0, 0, 0)

__device__ __forceinline__ u16 f2bf(float x) {
    union { float f; unsigned u; } v; v.f = x;
    unsigned r = v.u + 0x7fffu + ((v.u >> 16) & 1u);
    return (u16)(r >> 16);
}
__device__ __forceinline__ float bf2f(u16 h) {
    union { unsigned u; float f; } v; v.u = ((unsigned)h) << 16;
    return v.f;
}
// swizzled ushort index into [rows][256] tile; c8 = 8-elem group, low3 = within-group
__device__ __forceinline__ int ix256(int r, int c8, int c0) {
    return r * 256 + (((c8) ^ (r & 7)) << 3) + c0;
}
__device__ __forceinline__ int ix64(int r, int c8, int c0) {
    return r * 64 + (((c8) ^ (r & 7)) << 3) + c0;
}

__global__ __launch_bounds__(256, 1)
void capsule_mfma_kernel(const float* __restrict__ kin,
                         const float* __restrict__ qin,
                         const float* __restrict__ vin,
                         const float* __restrict__ g1,
                         const float* __restrict__ b1,
                         const float* __restrict__ g2,
                         const float* __restrict__ b2,
                         float* __restrict__ out)
{
    // 150,528 B total LDS
    __shared__ __align__(16) u16 kh[64 * 256];   // 32 KB  kn hi
    __shared__ __align__(16) u16 kl[64 * 256];   // 32 KB  kn lo
    __shared__ __align__(16) u16 qh[64 * 256];   // 32 KB  qn hi  / wT hi [256][64]
    __shared__ __align__(16) u16 ql[64 * 256];   // 32 KB  qn lo  / wT lo
    __shared__ __align__(16) u16 mh[64 * 64];    // 8 KB   m hi   / epilogue redA (float)
    __shared__ __align__(16) u16 ml[64 * 64];    // 8 KB   m lo   / epilogue redB (float)
    __shared__ float c1f[256], c2f[256];
    __shared__ float muA[64], invA[64], mu2[64], inv2[64];

    const int tid = threadIdx.x;
    const int wid = tid >> 6;         // wave 0..3
    const int l   = tid & 63;         // lane
    const int g   = l >> 4;           // quarter-wave 0..3
    const int l15 = l & 15;
    const int b   = blockIdx.x >> 4;
    const int kt  = blockIdx.x & 15;

    const float* kb = kin + (size_t)(b * 1024 + kt * 64) * 256;
    const float* qb = qin + (size_t)b * 1024 * 256;
    const float* vb = vin + (size_t)b * 1024 * 256;

    // ---------------- prologue: stage+normalize+split K tile ----------------
    {
        #pragma unroll
        for (int i = 0; i < 16; ++i) {
            const int r = i * 4 + wid;
            float4 x = *(const float4*)(kb + r * 256 + l * 4);
            float ssq = x.x * x.x + x.y * x.y + x.z * x.z + x.w * x.w;
            #pragma unroll
            for (int s = 1; s < 64; s <<= 1) ssq += __shfl_xor(ssq, s);
            const float sc = rsqrtf(fmaxf(ssq, 1e-12f));
            x.x *= sc; x.y *= sc; x.z *= sc; x.w *= sc;
            u16 h0 = f2bf(x.x), h1 = f2bf(x.y), h2 = f2bf(x.z), h3 = f2bf(x.w);
            u16x4 hh = {h0, h1, h2, h3};
            u16x4 ll = {f2bf(x.x - bf2f(h0)), f2bf(x.y - bf2f(h1)),
                        f2bf(x.z - bf2f(h2)), f2bf(x.w - bf2f(h3))};
            const int idx = ix256(r, l >> 1, (l & 1) * 4);
            *(u16x4*)(kh + idx) = hh;
            *(u16x4*)(kl + idx) = ll;
        }
    }

    // persistent state
    f32x4 acc[4][4];                  // out^T frags [fi d][fk k]
    #pragma unroll
    for (int i = 0; i < 4; ++i)
        #pragma unroll
        for (int j = 0; j < 4; ++j) acc[i][j] = (f32x4){0.f, 0.f, 0.f, 0.f};
    float rsp[4]  = {0.f, 0.f, 0.f, 0.f};   // LN1 raw row-sum partials (per reg e)
    float rssp[4] = {0.f, 0.f, 0.f, 0.f};
    float c1p[4]  = {0.f, 0.f, 0.f, 0.f};   // per-lane d = d0*64 + l
    float c2p[4]  = {0.f, 0.f, 0.f, 0.f};

    #pragma unroll 1
    for (int qt = 0; qt < 16; ++qt) {
        const int qoff = qt * 64;
        __syncthreads();   // prior G2 done with wT(qh/ql); (t=0: nothing)

        // ---- stage+normalize+split q tile into qh/ql ----
        #pragma unroll
        for (int i = 0; i < 16; ++i) {
            const int r = i * 4 + wid;
            float4 x = *(const float4*)(qb + (size_t)(qoff + r) * 256 + l * 4);
            float ssq = x.x * x.x + x.y * x.y + x.z * x.z + x.w * x.w;
            #pragma unroll
            for (int s = 1; s < 64; s <<= 1) ssq += __shfl_xor(ssq, s);
            const float sc = rsqrtf(fmaxf(ssq, 1e-12f));
            x.x *= sc; x.y *= sc; x.z *= sc; x.w *= sc;
            u16 h0 = f2bf(x.x), h1 = f2bf(x.y), h2 = f2bf(x.z), h3 = f2bf(x.w);
            u16x4 hh = {h0, h1, h2, h3};
            u16x4 ll = {f2bf(x.x - bf2f(h0)), f2bf(x.y - bf2f(h1)),
                        f2bf(x.z - bf2f(h2)), f2bf(x.w - bf2f(h3))};
            const int idx = ix256(r, l >> 1, (l & 1) * 4);
            *(u16x4*)(qh + idx) = hh;
            *(u16x4*)(ql + idx) = ll;
        }
        __syncthreads();   // qh/ql (and t=0: kh/kl) visible

        // ---- GEMM1: m[16w + g*4+e][fj*16 + l15] ----
        f32x4 macc[4];
        #pragma unroll
        for (int fj = 0; fj < 4; ++fj) macc[fj] = (f32x4){0.f, 0.f, 0.f, 0.f};
        const int arow = wid * 16 + l15;
        #pragma unroll
        for (int kk = 0; kk < 8; ++kk) {
            const int c8 = kk * 4 + g;
            const bf16x8 ah = *(const bf16x8*)(kh + ix256(arow, c8, 0));
            const bf16x8 al = *(const bf16x8*)(kl + ix256(arow, c8, 0));
            #pragma unroll
            for (int fj = 0; fj < 4; ++fj) {
                const int brow = fj * 16 + l15;
                const bf16x8 bh = *(const bf16x8*)(qh + ix256(brow, c8, 0));
                const bf16x8 bl = *(const bf16x8*)(ql + ix256(brow, c8, 0));
                macc[fj] = MFMA(ah, bh, macc[fj]);
                macc[fj] = MFMA(ah, bl, macc[fj]);
                macc[fj] = MFMA(al, bh, macc[fj]);
            }
        }
        // LN1 raw stats + convert m to split-bf16 in mh/ml
        #pragma unroll
        for (int fj = 0; fj < 4; ++fj) {
            #pragma unroll
            for (int e = 0; e < 4; ++e) {
                const float v = macc[fj][e];
                rsp[e] += v; rssp[e] += v * v;
                const u16 h = f2bf(v);
                const u16 lo = f2bf(v - bf2f(h));
                const int row = wid * 16 + g * 4 + e;
                const int q = fj * 16 + l15;
                const int idx = ix64(row, (q >> 3), q & 7);
                mh[idx] = h; ml[idx] = lo;
            }
        }
        __syncthreads();   // mh/ml visible; all waves done reading qh/ql

        // ---- stage w = g1*v transposed: wT[d][q] into qh/ql ----
        #pragma unroll
        for (int q0 = 0; q0 < 4; ++q0) {
            const int qq = wid * 16 + q0 * 4;   // 4-aligned q within tile
            const float g1v0 = g1[qoff + qq], g1v1 = g1[qoff + qq + 1];
            const float g1v2 = g1[qoff + qq + 2], g1v3 = g1[qoff + qq + 3];
            const float b1v0 = b1[qoff + qq], b1v1 = b1[qoff + qq + 1];
            const float b1v2 = b1[qoff + qq + 2], b1v3 = b1[qoff + qq + 3];
            #pragma unroll
            for (int d0 = 0; d0 < 4; ++d0) {
                const int d = d0 * 64 + l;
                const float x0 = vb[(size_t)(qoff + qq + 0) * 256 + d];
                const float x1 = vb[(size_t)(qoff + qq + 1) * 256 + d];
                const float x2 = vb[(size_t)(qoff + qq + 2) * 256 + d];
                const float x3 = vb[(size_t)(qoff + qq + 3) * 256 + d];
                const float w0 = g1v0 * x0, w1 = g1v1 * x1, w2 = g1v2 * x2, w3 = g1v3 * x3;
                c1p[d0] += w0 + w1 + w2 + w3;
                c2p[d0] += b1v0 * x0 + b1v1 * x1 + b1v2 * x2 + b1v3 * x3;
                u16 h0 = f2bf(w0), h1 = f2bf(w1), h2 = f2bf(w2), h3 = f2bf(w3);
                u16x4 hh = {h0, h1, h2, h3};
                u16x4 ll = {f2bf(w0 - bf2f(h0)), f2bf(w1 - bf2f(h1)),
                            f2bf(w2 - bf2f(h2)), f2bf(w3 - bf2f(h3))};
                const int idx = ix64(d, qq >> 3, qq & 7);   // 4-run within 8-group
                *(u16x4*)(qh + idx) = hh;
                *(u16x4*)(ql + idx) = ll;
            }
        }
        __syncthreads();   // wT visible

        // ---- GEMM2: out^T[64w + fi*16 + g*4+e][fk*16 + l15] += wT x m ----
        #pragma unroll
        for (int kk2 = 0; kk2 < 2; ++kk2) {
            const int c8 = kk2 * 4 + g;
            bf16x8 awh[4], awl[4], bmh[4], bml[4];
            #pragma unroll
            for (int fi = 0; fi < 4; ++fi) {
                const int drow = wid * 64 + fi * 16 + l15;
                awh[fi] = *(const bf16x8*)(qh + ix64(drow, c8, 0));
                awl[fi] = *(const bf16x8*)(ql + ix64(drow, c8, 0));
            }
            #pragma unroll
            for (int fk = 0; fk < 4; ++fk) {
                const int krow = fk * 16 + l15;
                bmh[fk] = *(const bf16x8*)(mh + ix64(krow, c8, 0));
                bml[fk] = *(const bf16x8*)(ml + ix64(krow, c8, 0));
            }
            #pragma unroll
            for (int fi = 0; fi < 4; ++fi)
                #pragma unroll
                for (int fk = 0; fk < 4; ++fk) {
                    acc[fi][fk] = MFMA(awh[fi], bmh[fk], acc[fi][fk]);
                    acc[fi][fk] = MFMA(awh[fi], bml[fk], acc[fi][fk]);
                    acc[fi][fk] = MFMA(awl[fi], bmh[fk], acc[fi][fk]);
                }
        }
    }

    // ================= epilogue =================
    __syncthreads();   // all G2 reads of mh/ml done -> reuse as float scratch
    float* redA = (float*)mh;   // [4][256] c1 partials, later [4][64] LN2 s
    float* redB = (float*)ml;

    #pragma unroll
    for (int d0 = 0; d0 < 4; ++d0) {
        redA[wid * 256 + d0 * 64 + l] = c1p[d0];
        redB[wid * 256 + d0 * 64 + l] = c2p[d0];
    }
    // LN1 stats: reduce rsp/rssp over l15 (q-direction)
    #pragma unroll
    for (int e = 0; e < 4; ++e) {
        float s = rsp[e], ss = rssp[e];
        s += __shfl_xor(s, 1);  ss += __shfl_xor(ss, 1);
        s += __shfl_xor(s, 2);  ss += __shfl_xor(ss, 2);
        s += __shfl_xor(s, 4);  ss += __shfl_xor(ss, 4);
        s += __shfl_xor(s, 8);  ss += __shfl_xor(ss, 8);
        if (l15 == 0) {
            const int k = wid * 16 + g * 4 + e;
            const float mu = s * (1.f / 1024.f);
            const float var = ss * (1.f / 1024.f) - mu * mu;
            muA[k] = mu;
            invA[k] = rsqrtf(var + 1e-3f);
        }
    }
    __syncthreads();
    {
        const float c1s = redA[tid] + redA[256 + tid] + redA[512 + tid] + redA[768 + tid];
        const float c2s = redB[tid] + redB[256 + tid] + redB[512 + tid] + redB[768 + tid];
        c1f[tid] = c1s;
        c2f[tid] = c2s;
    }
    __syncthreads();

    // LN1-fixup in registers + LN2 partial stats
    float s2p[4] = {0.f, 0.f, 0.f, 0.f}, ss2p[4] = {0.f, 0.f, 0.f, 0.f};
    #pragma unroll
    for (int fi = 0; fi < 4; ++fi) {
        const int dbase = wid * 64 + fi * 16 + g * 4;
        const float4 c1v = *(const float4*)(c1f + dbase);
        const float4 c2v = *(const float4*)(c2f + dbase);
        #pragma unroll
        for (int fk = 0; fk < 4; ++fk) {
            const int k = fk * 16 + l15;
            const float mu = muA[k], inv = invA[k];
            float pre;
            pre = inv * (acc[fi][fk][0] - mu * c1v.x) + c2v.x; acc[fi][fk][0] = pre;
            s2p[fk] += pre; ss2p[fk] += pre * pre;
            pre = inv * (acc[fi][fk][1] - mu * c1v.y) + c2v.y; acc[fi][fk][1] = pre;
            s2p[fk] += pre; ss2p[fk] += pre * pre;
            pre = inv * (acc[fi][fk][2] - mu * c1v.z) + c2v.z; acc[fi][fk][2] = pre;
            s2p[fk] += pre; ss2p[fk] += pre * pre;
            pre = inv * (acc[fi][fk][3] - mu * c1v.w) + c2v.w; acc[fi][fk][3] = pre;
            s2p[fk] += pre; ss2p[fk] += pre * pre;
        }
    }
    __syncthreads();   // redA/redB free for LN2 reuse
    #pragma unroll
    for (int fk = 0; fk < 4; ++fk) {
        float s = s2p[fk], ss = ss2p[fk];
        s += __shfl_xor(s, 16); ss += __shfl_xor(ss, 16);
        s += __shfl_xor(s, 32); ss += __shfl_xor(ss, 32);
        if (g == 0) {   // l < 16
            redA[wid * 64 + fk * 16 + l15] = s;
            redB[wid * 64 + fk * 16 + l15] = ss;
        }
    }
    __syncthreads();
    if (tid < 64) {
        const float s  = redA[tid] + redA[64 + tid] + redA[128 + tid] + redA[192 + tid];
        const float ss = redB[tid] + redB[64 + tid] + redB[128 + tid] + redB[192 + tid];
        const float mu = s * (1.f / 256.f);
        const float var = ss * (1.f / 256.f) - mu * mu;
        mu2[tid] = mu;
        inv2[tid] = rsqrtf(var + 1e-3f);
    }
    __syncthreads();

    // final LN2 apply + store (out^T frags -> row-major out)
    #pragma unroll
    for (int fi = 0; fi < 4; ++fi) {
        const int dbase = wid * 64 + fi * 16 + g * 4;
        const float4 gv = *(const float4*)(g2 + dbase);
        const float4 bv = *(const float4*)(b2 + dbase);
        #pragma unroll
        for (int fk = 0; fk < 4; ++fk) {
            const int k = fk * 16 + l15;
            const float mu = mu2[k], inv = inv2[k];
            float4 o;
            o.x = (acc[fi][fk][0] - mu) * inv * gv.x + bv.x;
            o.y = (acc[fi][fk][1] - mu) * inv * gv.y + bv.y;
            o.z = (acc[fi][fk][2] - mu) * inv * gv.z + bv.z;
            o.w = (acc[fi][fk][3] - mu) * inv * gv.w + bv.w;
            *(float4*)(out + (size_t)(b * 1024 + kt * 64 + k) * 256 + dbase) = o;
        }
    }
}

extern "C" void kernel_launch(void* const* d_in, const int* in_sizes, int n_in,
                              void* d_out, int out_size, void* d_ws, size_t ws_size,
                              hipStream_t stream) {
    const float* kin = (const float*)d_in[0];
    const float* qin = (const float*)d_in[1];
    const float* vin = (const float*)d_in[2];
    const float* g1  = (const float*)d_in[3];
    const float* b1  = (const float*)d_in[4];
    const float* g2  = (const float*)d_in[5];
    const float* b2  = (const float*)d_in[6];
    float* out = (float*)d_out;

    hipLaunchKernelGGL(capsule_mfma_kernel, dim3(512), dim3(256), 0, stream,
                       kin, qin, vin, g1, b1, g2, b2, out);
}